// Round 5
// baseline (369.433 us; speedup 1.0000x reference)
//
#include <hip/hip_runtime.h>

#define HH 512
#define WW 512
#define BB 4
#define SH 64
#define SW 64
#define NPRE 128
#define LAMV 0.24f
#define EPSV 1e-8f

typedef unsigned long long u64;

// ---------------- prep: cv / ch edge weights (unchanged, verified) ----------------
__global__ __launch_bounds__(256) void prep_kernel(
    const float* __restrict__ image, const float* __restrict__ ybic,
    const float* __restrict__ logk,
    float* __restrict__ cv, float* __restrict__ ch)
{
    int idx = blockIdx.x * 256 + threadIdx.x;
    if (idx >= BB * HH * WW) return;
    int x = idx % WW;
    int y = (idx / WW) % HH;
    int b = idx / (WW * HH);

    float K = expf(logk[0]);
    float invK2 = 1.0f / (K * K);

    const float* img = image + (size_t)b * 3 * HH * WW;
    const float* yb  = ybic  + (size_t)b * HH * WW;

    float f0 = img[y * WW + x];
    float f1 = img[HH * WW + y * WW + x];
    float f2 = img[2 * HH * WW + y * WW + x];
    float f3 = yb[y * WW + x];

    if (y < HH - 1) {
        float s = fabsf(img[(y + 1) * WW + x] - f0)
                + fabsf(img[HH * WW + (y + 1) * WW + x] - f1)
                + fabsf(img[2 * HH * WW + (y + 1) * WW + x] - f2)
                + fabsf(yb[(y + 1) * WW + x] - f3);
        s *= 0.25f;
        cv[(size_t)b * (HH - 1) * WW + y * WW + x] = 1.0f / (1.0f + s * s * invK2);
    }
    if (x < WW - 1) {
        float s = fabsf(img[y * WW + x + 1] - f0)
                + fabsf(img[HH * WW + y * WW + x + 1] - f1)
                + fabsf(img[2 * HH * WW + y * WW + x + 1] - f2)
                + fabsf(yb[y * WW + x + 1] - f3);
        s *= 0.25f;
        ch[(size_t)b * HH * (WW - 1) + y * (WW - 1) + x] = 1.0f / (1.0f + s * s * invK2);
    }
}

// halo slot: [parity][edge][b][tileY][tileX][64 x u64]; edges 0=Top,1=Bot,2=Lft,3=Rgt
// each u64 = {gen:u32 (hi), val:f32 bits (lo)} -> 1 MB total
__device__ __forceinline__ u64* hslot(u64* halo, int p, int e, int b, int tY, int tX) {
    return halo + ((size_t)(((p * 4 + e) * BB + b) * 64 + tY * 8 + tX)) * 64;
}

__device__ __forceinline__ void st_tag(u64* p, float v, unsigned g) {
    u64 w = ((u64)g << 32) | (u64)__builtin_bit_cast(unsigned, v);
    __hip_atomic_store(p, w, __ATOMIC_RELAXED, __HIP_MEMORY_SCOPE_AGENT);
}

// poll 4 tagged words until ALL carry the expected generation (exact match:
// stale gens from prior calls / 0xAA poison can never equal the current gen)
__device__ __forceinline__ void poll4(u64* e, unsigned gen, float out[4]) {
    u64 w0, w1, w2, w3;
    for (;;) {
        w0 = __hip_atomic_load(e + 0, __ATOMIC_RELAXED, __HIP_MEMORY_SCOPE_AGENT);
        w1 = __hip_atomic_load(e + 1, __ATOMIC_RELAXED, __HIP_MEMORY_SCOPE_AGENT);
        w2 = __hip_atomic_load(e + 2, __ATOMIC_RELAXED, __HIP_MEMORY_SCOPE_AGENT);
        w3 = __hip_atomic_load(e + 3, __ATOMIC_RELAXED, __HIP_MEMORY_SCOPE_AGENT);
        if ((unsigned)(w0 >> 32) == gen && (unsigned)(w1 >> 32) == gen &&
            (unsigned)(w2 >> 32) == gen && (unsigned)(w3 >> 32) == gen) break;
    }
    out[0] = __builtin_bit_cast(float, (unsigned)w0);
    out[1] = __builtin_bit_cast(float, (unsigned)w1);
    out[2] = __builtin_bit_cast(float, (unsigned)w2);
    out[3] = __builtin_bit_cast(float, (unsigned)w3);
}

// ---------------- persistent kernel: 128 iterations, tagged-data handshakes ----------------
// Grid (8,8,4), 256 threads; thread = 4x4 px; WG = 64x64 tile; all 256 WGs resident
// (32KB LDS, 4 waves -> >=5 WGs/CU capacity). One __syncthreads per iteration
// (LDS edge buffers parity-double-buffered).
__global__ __launch_bounds__(256) void persist_kernel(
    const float* __restrict__ ybic, float* __restrict__ out_img,
    const float* __restrict__ cv, const float* __restrict__ ch,
    const float* __restrict__ src, const float* __restrict__ mask,
    u64* __restrict__ halo)
{
    const int b = blockIdx.z, tileY = blockIdx.y, tileX = blockIdx.x;
    const int tid = threadIdx.x;
    const int tx = tid & 15, ty = tid >> 4;
    const int y0 = tileY * 64 + ty * 4, x0 = tileX * 64 + tx * 4;

    // ---- load state into registers ----
    float I[4][4];
    #pragma unroll
    for (int r = 0; r < 4; ++r) {
        float4 t = *(const float4*)(ybic + ((size_t)b * HH + y0 + r) * WW + x0);
        I[r][0] = t.x; I[r][1] = t.y; I[r][2] = t.z; I[r][3] = t.w;
    }
    float cvaL[5][4];   // lambda * cv at interfaces y0-1 .. y0+3
    #pragma unroll
    for (int i = 0; i < 5; ++i) {
        int y = y0 - 1 + i;
        if (y >= 0 && y < HH - 1) {
            float4 t = *(const float4*)(cv + ((size_t)b * (HH - 1) + y) * WW + x0);
            cvaL[i][0] = t.x * LAMV; cvaL[i][1] = t.y * LAMV;
            cvaL[i][2] = t.z * LAMV; cvaL[i][3] = t.w * LAMV;
        } else {
            #pragma unroll
            for (int c = 0; c < 4; ++c) cvaL[i][c] = 0.0f;
        }
    }
    float chaL[4][5];   // lambda * ch at interfaces x0-1 .. x0+3
    #pragma unroll
    for (int r = 0; r < 4; ++r) {
        const float* row = ch + ((size_t)b * HH + y0 + r) * (WW - 1);
        #pragma unroll
        for (int j = 0; j < 5; ++j) {
            int x = x0 - 1 + j;
            chaL[r][j] = ((unsigned)x <= (unsigned)(WW - 2)) ? row[x] * LAMV : 0.0f;
        }
    }
    const size_t sidx = ((size_t)b * SH + (y0 >> 3)) * SW + (x0 >> 3);
    const float sv = src[sidx];
    const bool useR = (mask[sidx] >= 0.5f);

    // parity-double-buffered LDS edge exchange (intra-WG halo): 32 KB
    __shared__ float topE[2][16][16][4];
    __shared__ float botE[2][16][16][4];
    __shared__ float lftE[2][16][16][4];
    __shared__ float rgtE[2][16][16][4];

    const bool pubT = (ty == 0)  && (tileY > 0);
    const bool pubB = (ty == 15) && (tileY < 7);
    const bool pubL = (tx == 0)  && (tileX > 0);
    const bool pubR = (tx == 15) && (tileX < 7);

    #pragma unroll 1
    for (int k = 0; k < NPRE; ++k) {
        const int p = k & 1;
        const unsigned gen = (unsigned)(k + 1);

        // ---- publish: global tagged edges first (fire-and-forget), then LDS ----
        if (pubT) {
            u64* e = hslot(halo, p, 0, b, tileY, tileX) + tx * 4;
            st_tag(e + 0, I[0][0], gen); st_tag(e + 1, I[0][1], gen);
            st_tag(e + 2, I[0][2], gen); st_tag(e + 3, I[0][3], gen);
        }
        if (pubB) {
            u64* e = hslot(halo, p, 1, b, tileY, tileX) + tx * 4;
            st_tag(e + 0, I[3][0], gen); st_tag(e + 1, I[3][1], gen);
            st_tag(e + 2, I[3][2], gen); st_tag(e + 3, I[3][3], gen);
        }
        if (pubL) {
            u64* e = hslot(halo, p, 2, b, tileY, tileX) + ty * 4;
            st_tag(e + 0, I[0][0], gen); st_tag(e + 1, I[1][0], gen);
            st_tag(e + 2, I[2][0], gen); st_tag(e + 3, I[3][0], gen);
        }
        if (pubR) {
            u64* e = hslot(halo, p, 3, b, tileY, tileX) + ty * 4;
            st_tag(e + 0, I[0][3], gen); st_tag(e + 1, I[1][3], gen);
            st_tag(e + 2, I[2][3], gen); st_tag(e + 3, I[3][3], gen);
        }
        #pragma unroll
        for (int c = 0; c < 4; ++c) {
            topE[p][ty][tx][c] = I[0][c];
            botE[p][ty][tx][c] = I[3][c];
            lftE[p][ty][tx][c] = I[c][0];
            rgtE[p][ty][tx][c] = I[c][3];
        }
        __syncthreads();   // LDS buf[p] complete (also spaces buf re-use 2 barriers apart)

        // ---- gather halos ----
        float up[4], dn[4], lf[4], rg[4];
        if (ty > 0) {
            #pragma unroll
            for (int c = 0; c < 4; ++c) up[c] = botE[p][ty - 1][tx][c];
        } else if (tileY > 0) {
            poll4(hslot(halo, p, 1, b, tileY - 1, tileX) + tx * 4, gen, up);
        } else { up[0] = up[1] = up[2] = up[3] = 0.0f; }

        if (ty < 15) {
            #pragma unroll
            for (int c = 0; c < 4; ++c) dn[c] = topE[p][ty + 1][tx][c];
        } else if (tileY < 7) {
            poll4(hslot(halo, p, 0, b, tileY + 1, tileX) + tx * 4, gen, dn);
        } else { dn[0] = dn[1] = dn[2] = dn[3] = 0.0f; }

        if (tx > 0) {
            #pragma unroll
            for (int r = 0; r < 4; ++r) lf[r] = rgtE[p][ty][tx - 1][r];
        } else if (tileX > 0) {
            poll4(hslot(halo, p, 3, b, tileY, tileX - 1) + ty * 4, gen, lf);
        } else { lf[0] = lf[1] = lf[2] = lf[3] = 0.0f; }

        if (tx < 15) {
            #pragma unroll
            for (int r = 0; r < 4; ++r) rg[r] = lftE[p][ty][tx + 1][r];
        } else if (tileX < 7) {
            poll4(hslot(halo, p, 2, b, tileY, tileX + 1) + ty * 4, gen, rg);
        } else { rg[0] = rg[1] = rg[2] = rg[3] = 0.0f; }

        // ---- diffuse + block mean + adjust (all registers) ----
        float nv[4][4];
        float s = 0.0f;
        #pragma unroll
        for (int r = 0; r < 4; ++r) {
            #pragma unroll
            for (int c = 0; c < 4; ++c) {
                const float v = I[r][c];
                const float u = r       ? I[r - 1][c] : up[c];
                const float d = (r < 3) ? I[r + 1][c] : dn[c];
                const float l = c       ? I[r][c - 1] : lf[r];
                const float g = (c < 3) ? I[r][c + 1] : rg[r];
                const float t = cvaL[r + 1][c] * (d - v)
                              - cvaL[r][c]     * (v - u)
                              + chaL[r][c + 1] * (g - v)
                              - chaL[r][c]     * (v - l);
                const float w = v + t;
                nv[r][c] = w;
                s += w;
            }
        }
        // 8x8 block = 2x2 thread group (lanes ^1 and ^16, same wave)
        s += __shfl_xor(s, 1);
        s += __shfl_xor(s, 16);
        const float mean  = s * (1.0f / 64.0f);
        const float ratio = useR ? (sv / (mean + EPSV)) : 1.0f;
        #pragma unroll
        for (int r = 0; r < 4; ++r)
            #pragma unroll
            for (int c = 0; c < 4; ++c) I[r][c] = nv[r][c] * ratio;
    }

    // ---- store final image ----
    #pragma unroll
    for (int r = 0; r < 4; ++r)
        *(float4*)(out_img + ((size_t)b * HH + y0 + r) * WW + x0) =
            make_float4(I[r][0], I[r][1], I[r][2], I[r][3]);
}

extern "C" void kernel_launch(void* const* d_in, const int* in_sizes, int n_in,
                              void* d_out, int out_size, void* d_ws, size_t ws_size,
                              hipStream_t stream) {
    const float* image  = (const float*)d_in[0];
    const float* source = (const float*)d_in[1];
    const float* mask   = (const float*)d_in[2];
    const float* ybic   = (const float*)d_in[3];
    const float* logk   = (const float*)d_in[4];

    float* out_img = (float*)d_out;                          // [B,1,H,W]
    float* out_cv  = out_img + (size_t)BB * HH * WW;         // [B,1,H-1,W]
    float* out_ch  = out_cv + (size_t)BB * (HH - 1) * WW;    // [B,1,H,W-1]

    u64* halo = (u64*)d_ws;    // 1 MB of tagged edge slots; no reset needed
                               // (exact-gen match makes stale tags unmatchable)

    int total = BB * HH * WW;
    prep_kernel<<<(total + 255) / 256, 256, 0, stream>>>(image, ybic, logk, out_cv, out_ch);

    dim3 grid(WW / 64, HH / 64, BB);
    persist_kernel<<<grid, 256, 0, stream>>>(ybic, out_img, out_cv, out_ch,
                                             source, mask, halo);
}